// Round 16
// baseline (2604.757 us; speedup 1.0000x reference)
//
#include <hip/hip_runtime.h>
#include <hip/hip_bf16.h>
#include <stdint.h>

// ---------------------------------------------------------------------------
// Seq2seq LSTM (2-layer enc + 2-layer dec, B=32, S=T=128, E=512, H=1024).
//   gather_emb -> bf16 X
//   gemm_xp: XP = X @ Wih0^T + bias, bf16, layout [t][blk][hl][g][b]
//   rnn_pair: ONE dispatch per enc/dec, 256 blocks x 320 threads.
//   R14 champion compute path. ONE structural change: DEDICATED SYNC WAVE.
//   Waves 0-3 = compute (identical math); wave 4 polls flags ONLY (never has
//   bulk loads in flight -- R15 showed per-wave in-order VMEM returns make
//   poll-behind-loads a disaster). Per step: wave4 polls ALL conditions
//   while wave0 publishes the previous step -> barrier A -> compute waves
//   hoist x+h loads (64 deep) + 64 MFMAs + pointwise -> barrier B ->
//   wave0-only publish {stores, own drain, flag release}.
// Sequential grid-sync epochs: 256.
// ---------------------------------------------------------------------------

typedef __attribute__((ext_vector_type(8))) __bf16 bf16x8;
typedef __attribute__((ext_vector_type(4))) __bf16 bf16x4;
typedef __attribute__((ext_vector_type(4))) float  f32x4;

#define SLAB 32768   // bf16 elems per h slab: [128 j][32 b][8 col] = 64KB
// LDS: Wxh slice 64KB + Whh slice 64KB + sP (256 bf16)
#define RNN_SMEM (65536 + 65536 + 512)

__device__ __forceinline__ float sigmoidf_(float x) {
  return 1.f / (1.f + __expf(-x));
}
__device__ __forceinline__ float tanhf_(float x) {
  float e = __expf(-2.f * fabsf(x));
  float t = (1.f - e) / (1.f + e);
  return x < 0.f ? -t : t;
}

// ---------------------------------------------------------------------------
__global__ void init_ws(float* zeros, unsigned* flags) {
  int i = blockIdx.x * 256 + threadIdx.x;
  if (i < 32 * 1024) zeros[i] = 0.f;
  if (i < 512) flags[i] = 0u;          // 4 layers x 128 packed flags
}

// ---------------------------------------------------------------------------
__global__ void gather_emb(const int* __restrict__ src, const int* __restrict__ tgt,
                           const float* __restrict__ ee, const float* __restrict__ de,
                           __bf16* __restrict__ Xe, __bf16* __restrict__ Xd) {
  int row = blockIdx.x & 4095;
  int t = row >> 5, b = row & 31;
  bool isd = blockIdx.x >= 4096;
  int tok = isd ? (t == 0 ? 1 : tgt[b * 128 + t - 1]) : src[b * 128 + t];
  const float* ep = (isd ? de : ee) + (size_t)tok * 512;
  __bf16* op = (isd ? Xd : Xe) + (size_t)row * 512;
  int i = threadIdx.x * 4;
  float4 v = *(const float4*)(ep + i);
  bf16x4 t4;
  t4[0] = (__bf16)v.x; t4[1] = (__bf16)v.y; t4[2] = (__bf16)v.z; t4[3] = (__bf16)v.w;
  *(bf16x4*)(op + i) = t4;
}

// ---------------------------------------------------------------------------
// XP = A[M=4096,K=512](bf16) @ W[4096,K]^T(f32->bf16) + bih + bhh  (bf16 out)
// Output layout: XP[t][blk][hl][g][b]  (t=row>>5, b=row&31, col=g*1024+blk*8+hl)
__global__ __launch_bounds__(256) void gemm_xp(
    const __bf16* __restrict__ A, const float* __restrict__ W,
    const float* __restrict__ bih, const float* __restrict__ bhh,
    __bf16* __restrict__ C, int K) {
  __shared__ char sA[128 * 64 * 2];
  __shared__ char sB[128 * 64 * 2];
  int tid = threadIdx.x;
  int lane = tid & 63, wave = tid >> 6;
  int wm = wave & 1, wn = wave >> 1;
  int bm = blockIdx.x & 31, bn = blockIdx.x >> 5;
  int frow = lane & 15;
  int kj = (lane >> 4) * 16;

  f32x4 acc[4][4] = {};

  for (int k0 = 0; k0 < K; k0 += 64) {
#pragma unroll
    for (int c4 = 0; c4 < 4; ++c4) {   // stage A tile (bf16, swizzled)
      int idx = (c4 * 256 + tid) * 8;
      int r = idx >> 6, kk = idx & 63;
      bf16x8 v = *(const bf16x8*)(A + (size_t)(bm * 128 + r) * K + k0 + kk);
      *(bf16x8*)(sA + ((r * 128 + kk * 2) ^ ((r & 7) << 4))) = v;
    }
#pragma unroll
    for (int c4 = 0; c4 < 4; ++c4) {   // stage B tile (f32 -> bf16, swizzled)
      int idx = (c4 * 256 + tid) * 8;
      int r = idx >> 6, kk = idx & 63;
      const float* wp = W + (size_t)(bn * 128 + r) * K + k0 + kk;
      float4 w0 = *(const float4*)wp;
      float4 w1 = *(const float4*)(wp + 4);
      bf16x8 v;
      v[0] = (__bf16)w0.x; v[1] = (__bf16)w0.y; v[2] = (__bf16)w0.z; v[3] = (__bf16)w0.w;
      v[4] = (__bf16)w1.x; v[5] = (__bf16)w1.y; v[6] = (__bf16)w1.z; v[7] = (__bf16)w1.w;
      *(bf16x8*)(sB + ((r * 128 + kk * 2) ^ ((r & 7) << 4))) = v;
    }
    __syncthreads();
#pragma unroll
    for (int half = 0; half < 2; ++half) {
      int kb = half * 64 + kj;
      bf16x8 af[4], bfr[4];
#pragma unroll
      for (int f = 0; f < 4; ++f) {
        int arr = wm * 64 + f * 16 + frow;
        af[f] = *(const bf16x8*)(sA + (arr * 128 + (kb ^ ((arr & 7) << 4))));
        int brr = wn * 64 + f * 16 + frow;
        bfr[f] = *(const bf16x8*)(sB + (brr * 128 + (kb ^ ((brr & 7) << 4))));
      }
#pragma unroll
      for (int fm = 0; fm < 4; ++fm)
#pragma unroll
        for (int fn = 0; fn < 4; ++fn)
          acc[fm][fn] = __builtin_amdgcn_mfma_f32_16x16x32_bf16(af[fm], bfr[fn],
                                                                acc[fm][fn], 0, 0, 0);
    }
    __syncthreads();
  }
  int cm = bm * 128 + wm * 64, cn = bn * 128 + wn * 64;
#pragma unroll
  for (int fn = 0; fn < 4; ++fn) {
    int col = cn + fn * 16 + frow;
    int g = col >> 10, hcol = col & 1023;
    int blkd = hcol >> 3, hl = hcol & 7;
    float bias = bih[col] + bhh[col];
#pragma unroll
    for (int fm = 0; fm < 4; ++fm) {
      int r0 = cm + fm * 16 + ((lane >> 4) << 2);
#pragma unroll
      for (int j = 0; j < 4; ++j) {
        int row = r0 + j;
        // XP[t][blk][hl][g][b]
        C[(size_t)(row >> 5) * 131072 + blkd * 1024 + hl * 128 + g * 32 +
          (row & 31)] = (__bf16)(acc[fm][fn][j] + bias);
      }
    }
  }
}

// ---------------------------------------------------------------------------
struct RnnArgs {
  const float* Whh;       // [4096,1024] recurrent weights (f32)
  const float* Wxh;       // layer1: [4096,1024] input weights; layer0: nullptr
  const float* bih;       // layer1 bias (layer0: baked into XP)
  const float* bhh;
  const __bf16* XP;       // layer0: [t][blk][hl][g][b] bf16; layer1: nullptr
  const __bf16* xslab;    // layer1: [128][SLAB] lower layer's h slabs
  const unsigned* xflags; // layer1: lower layer's flags
  const __bf16* h0;       // [SLAB] initial h (slab layout)
  const float* c0;        // [32*1024] initial c
  __bf16* hseq;           // [128][SLAB]
  float* cfin;            // [32*1024]
  float* yout;            // nullptr or [B,T,H] f32
  unsigned* flags;        // [128] own produce flags (packed)
};

__device__ __forceinline__ void rnn_body(const RnnArgs& P, int blk, char* smem) {
  char*   sW0 = smem;                              // Wxh slice (layer1)
  char*   sW1 = smem + 65536;                      // Whh slice
  __bf16* sP  = (__bf16*)(smem + 131072);          // [256] publish repack

  int tid = threadIdx.x;
  int lane = tid & 63, wave = tid >> 6;            // wave 0..4
  bool syncw = (wave == 4);
  int mt = wave & 1, nt = (wave >> 1) & 1;         // valid for waves 0-3
  bool isL0 = (P.XP != nullptr);

  // one-time invalidate: kill stale L1/L2 lines from previous graph replays
  __builtin_amdgcn_fence(__ATOMIC_ACQUIRE, "agent");

  // ---- stage weight slices once (waves 0-3), rows HL-MAJOR (row = hl*4+g)
  if (tid < 256) {
    const float* srcs[2] = {P.Wxh, P.Whh};
    char* dsts[2] = {sW0, sW1};
    for (int s = (isL0 ? 1 : 0); s < 2; ++s) {
      for (int g = 0; g < 4; ++g) {
        const float* sp = srcs[s] + (size_t)(g * 1024 + blk * 8) * 1024;
#pragma unroll
        for (int it = 0; it < 8; ++it) {
          int e = (it * 256 + tid) * 4;
          int rl = e >> 10, k = e & 1023;
          float4 v = *(const float4*)(sp + e);
          bf16x4 t4;
          t4[0] = (__bf16)v.x; t4[1] = (__bf16)v.y;
          t4[2] = (__bf16)v.z; t4[3] = (__bf16)v.w;
          int r = rl * 4 + g;   // hl-major
          *(bf16x4*)(dsts[s] + ((r << 11) + ((k << 1) ^ ((r & 7) << 4)))) = t4;
        }
      }
    }
  }
  // barrier A of t=0 orders staging -> first reads.

  // ---- cell ownership (swapped-MFMA C layout, verified R8/R10-R14):
  // lane -> hl = mt*4 + (lane>>4), b = nt*16 + (lane&15); acc[0..3]=i,f,g,o
  int hl = mt * 4 + (lane >> 4);
  int b  = nt * 16 + (lane & 15);
  float c = 0.f;
  if (!syncw) c = P.c0[b * 1024 + blk * 8 + hl];

  // layer1: per-thread gate biases (layer0 has them baked into XP)
  float bI = 0.f, bF = 0.f, bG = 0.f, bO = 0.f;
  if (!isL0 && !syncw) {
    int col = blk * 8 + hl;
    bI = P.bih[col] + P.bhh[col];
    bF = P.bih[1024 + col] + P.bhh[1024 + col];
    bG = P.bih[2048 + col] + P.bhh[2048 + col];
    bO = P.bih[3072 + col] + P.bhh[3072 + col];
  }

  int rr  = mt * 16 + (lane & 15);       // A (weight) row within 32-row slice
  int swz = (rr & 7) << 4;
  const char* aRow0 = sW0 + (rr << 11);
  const char* aRow1 = sW1 + (rr << 11);
  int kj   = (lane >> 4) * 16;           // A k-byte offset
  int bsub = (lane >> 4) * 512 + b * 16; // B (h/x) slab sub-offset

  // L0 XP prefetch base (coalesced: [t][blk][hl][g][b])
  const __bf16* xpb = (isL0 && !syncw)
                          ? (P.XP + (size_t)blk * 1024 + hl * 128 + b) : nullptr;

  for (int t = 0; t < 128; ++t) {
    // ---- sync wave: poll ALL of step t's conditions (flag loads only --
    //      never queued behind bulk loads). Overlaps wave0's publish of t-1
    //      and the device-wide flag propagation tail.
    if (syncw) {
      if (t > 0 || !isL0) {
        unsigned th = (unsigned)t, tx = (unsigned)(t + 1);
        for (;;) {
          bool ok = true;
          if (!isL0)
            ok = (__hip_atomic_load(P.xflags + lane, __ATOMIC_RELAXED,
                                    __HIP_MEMORY_SCOPE_AGENT) >= tx) &&
                 (__hip_atomic_load(P.xflags + 64 + lane, __ATOMIC_RELAXED,
                                    __HIP_MEMORY_SCOPE_AGENT) >= tx);
          if (t > 0)
            ok = ok &&
                 (__hip_atomic_load(P.flags + lane, __ATOMIC_RELAXED,
                                    __HIP_MEMORY_SCOPE_AGENT) >= th) &&
                 (__hip_atomic_load(P.flags + 64 + lane, __ATOMIC_RELAXED,
                                    __HIP_MEMORY_SCOPE_AGENT) >= th);
          if (__all(ok)) break;
          __builtin_amdgcn_s_sleep(1);
        }
      }
    }

    float xi = bI, xf = bF, xg = bG, xo = bO;
    if (isL0 && !syncw) {   // XP prefetch (flag-independent, tiny)
      const __bf16* xr = xpb + (size_t)t * 131072;
      xi = (float)xr[0];  xf = (float)xr[32];
      xg = (float)xr[64]; xo = (float)xr[96];
    }

    __syncthreads();   // A: step-t data confirmed globally visible

    if (!syncw) {
      f32x4 acc = {0.f, 0.f, 0.f, 0.f};
      const char* hb = (const char*)((t == 0) ? P.h0
                         : (P.hseq + (size_t)(t - 1) * SLAB)) + bsub;
      if (!isL0) {
        // full 64-deep hoist: 32 x loads + 32 h loads, then 64 MFMAs
        const char* xb = (const char*)(P.xslab + (size_t)t * SLAB) + bsub;
        bf16x8 xv[32], hv[32];
#pragma unroll
        for (int u = 0; u < 32; ++u)
          xv[u] = *(const bf16x8*)(xb + (size_t)u * 2048);
#pragma unroll
        for (int u = 0; u < 32; ++u)
          hv[u] = *(const bf16x8*)(hb + (size_t)u * 2048);
#pragma unroll
        for (int u = 0; u < 32; ++u) {
          int kb = u * 64 + kj;
          bf16x8 av = *(const bf16x8*)(aRow0 + (kb ^ swz));
          acc = __builtin_amdgcn_mfma_f32_16x16x32_bf16(av, xv[u], acc, 0, 0, 0);
        }
#pragma unroll
        for (int u = 0; u < 32; ++u) {
          int kb = u * 64 + kj;
          bf16x8 av = *(const bf16x8*)(aRow1 + (kb ^ swz));
          acc = __builtin_amdgcn_mfma_f32_16x16x32_bf16(av, hv[u], acc, 0, 0, 0);
        }
      } else {
        bf16x8 hv[32];
#pragma unroll
        for (int u = 0; u < 32; ++u)
          hv[u] = *(const bf16x8*)(hb + (size_t)u * 2048);
#pragma unroll
        for (int u = 0; u < 32; ++u) {
          int kb = u * 64 + kj;
          bf16x8 av = *(const bf16x8*)(aRow1 + (kb ^ swz));
          acc = __builtin_amdgcn_mfma_f32_16x16x32_bf16(av, hv[u], acc, 0, 0, 0);
        }
      }
      // pointwise LSTM cell, fully in registers (acc = i,f,g,o)
      float gi = sigmoidf_(acc[0] + xi);
      float gf = sigmoidf_(acc[1] + xf);
      float gg = tanhf_(acc[2] + xg);
      float go = sigmoidf_(acc[3] + xo);
      c = gf * c + gi * gg;
      float h = go * tanhf_(c);
      sP[b * 8 + hl] = (__bf16)h;
    }
    __syncthreads();   // B: sP complete

    // ---- publish (champion): wave 0 only -- stores, OWN drain, flag.
    if (tid < 64) {
      unsigned long long v = *(const unsigned long long*)(sP + tid * 4);
      unsigned long long* dst = (unsigned long long*)(
          (char*)P.hseq + (size_t)t * 65536 + blk * 512 + tid * 8);
      __hip_atomic_store(dst, v, __ATOMIC_RELAXED, __HIP_MEMORY_SCOPE_AGENT);
      asm volatile("s_waitcnt vmcnt(0)" ::: "memory");
      if (tid == 0)
        __hip_atomic_store(P.flags + blk, (unsigned)(t + 1), __ATOMIC_RELEASE,
                           __HIP_MEMORY_SCOPE_AGENT);
    }
    // yout (final decoder layer only): coalesced from sP
    if (P.yout && tid < 256) {
      int yb = tid >> 3, yhl = tid & 7;
      P.yout[((size_t)yb * 128 + t) * 1024 + blk * 8 + yhl] =
          (float)sP[yb * 8 + yhl];
    }
  }
  if (!syncw) P.cfin[b * 1024 + blk * 8 + hl] = c;
}

// Blocks 0-127: layer0 (A). Blocks 128-255: layer1 (B), 1-step skewed.
__global__ __launch_bounds__(320, 1) void rnn_pair(RnnArgs A, RnnArgs B) {
  extern __shared__ char smem[];
  if (blockIdx.x < 128) rnn_body(A, blockIdx.x, smem);
  else                  rnn_body(B, blockIdx.x - 128, smem);
}

// ---------------------------------------------------------------------------
extern "C" void kernel_launch(void* const* d_in, const int* in_sizes, int n_in,
                              void* d_out, int out_size, void* d_ws, size_t ws_size,
                              hipStream_t stream) {
  (void)in_sizes; (void)n_in; (void)out_size; (void)ws_size;
  const int*   src     = (const int*)d_in[0];
  const int*   tgt     = (const int*)d_in[1];
  const float* enc_emb = (const float*)d_in[2];
  const float* dec_emb = (const float*)d_in[3];
  const float* W[16];
  for (int i = 0; i < 16; ++i) W[i] = (const float*)d_in[4 + i];
  // enc: Wih0=W[0] Whh0=W[1] bih0=W[2] bhh0=W[3]  Wih1=W[4] Whh1=W[5] b=W[6],W[7]
  // dec: Wih0=W[8] Whh0=W[9] b=W[10],W[11]        Wih1=W[12] Whh1=W[13] b=W[14],W[15]

  char* ws = (char*)d_ws;
  size_t off = 0;
  auto alloc = [&](size_t bytes) {
    char* p = ws + off;
    off += (bytes + 255) & ~(size_t)255;
    return p;
  };
  unsigned* flags = (unsigned*)alloc((size_t)4 * 128 * sizeof(unsigned));
  float*    zeros = (float*)alloc((size_t)32 * 1024 * 4);
  __bf16*   Xe   = (__bf16*)alloc((size_t)4096 * 512 * 2);
  __bf16*   Xd   = (__bf16*)alloc((size_t)4096 * 512 * 2);
  __bf16*   XP1  = (__bf16*)alloc((size_t)4096 * 4096 * 2);
  __bf16*   XP2  = (__bf16*)alloc((size_t)4096 * 4096 * 2);
  __bf16*   hE0  = (__bf16*)alloc((size_t)128 * SLAB * 2);
  __bf16*   hE1  = (__bf16*)alloc((size_t)128 * SLAB * 2);
  __bf16*   hD0  = (__bf16*)alloc((size_t)128 * SLAB * 2);
  __bf16*   hD1  = (__bf16*)alloc((size_t)128 * SLAB * 2);
  float*    cE0  = (float*)alloc((size_t)32 * 1024 * 4);
  float*    cE1  = (float*)alloc((size_t)32 * 1024 * 4);
  float*    cd0  = (float*)alloc((size_t)32 * 1024 * 4);
  float*    cd1  = (float*)alloc((size_t)32 * 1024 * 4);

  hipFuncSetAttribute((const void*)rnn_pair,
                      hipFuncAttributeMaxDynamicSharedMemorySize, RNN_SMEM);

  init_ws<<<128, 256, 0, stream>>>(zeros, flags);
  gather_emb<<<8192, 128, 0, stream>>>(src, tgt, enc_emb, dec_emb, Xe, Xd);

  // layer-0 x-parts (K=512) for both encoder and decoder, up front
  gemm_xp<<<1024, 256, 0, stream>>>(Xe, W[0], W[2], W[3], XP1, 512);
  gemm_xp<<<1024, 256, 0, stream>>>(Xd, W[8], W[10], W[11], XP2, 512);

  unsigned* fE0 = flags;
  unsigned* fE1 = flags + 128;
  unsigned* fD0 = flags + 256;
  unsigned* fD1 = flags + 384;

  // encoder epoch: L0 (blocks 0-127) + L1 skewed (blocks 128-255)
  RnnArgs e0{W[1], nullptr, nullptr, nullptr, XP1, nullptr, nullptr,
             (const __bf16*)zeros, zeros, hE0, cE0, nullptr, fE0};
  RnnArgs e1{W[5], W[4], W[6], W[7], nullptr, hE0, fE0,
             (const __bf16*)zeros, zeros, hE1, cE1, nullptr, fE1};
  rnn_pair<<<256, 320, RNN_SMEM, stream>>>(e0, e1);

  // decoder epoch: L0 init = encL0 finals, L1 init = encL1 finals -> d_out
  RnnArgs d0{W[9], nullptr, nullptr, nullptr, XP2, nullptr, nullptr,
             hE0 + (size_t)127 * SLAB, cE0, hD0, cd0, nullptr, fD0};
  RnnArgs d1{W[13], W[12], W[14], W[15], nullptr, hD0, fD0,
             hE1 + (size_t)127 * SLAB, cE1, hD1, cd1, (float*)d_out, fD1};
  rnn_pair<<<256, 320, RNN_SMEM, stream>>>(d0, d1);
}

// Round 17
// 2308.993 us; speedup vs baseline: 1.1281x; 1.1281x over previous
//
#include <hip/hip_runtime.h>
#include <hip/hip_bf16.h>
#include <stdint.h>

// ---------------------------------------------------------------------------
// Seq2seq LSTM (2-layer enc + 2-layer dec, B=32, S=T=128, E=512, H=1024).
//   gather_emb -> bf16 X
//   gemm_xp: XP = X @ Wih0^T + bias, bf16, layout [t][blk][hl][g][b]
//   rnn_pair: ONE dispatch per enc/dec, 256 blocks, layer0 + layer1 skewed.
//   == R14 champion (1799us) restored ==  (R13/R15/R16 structural probes all
//   regressed; per-wave in-order VMEM returns mean the polling wave must
//   never have bulk loads queued ahead of its flag loads.)
//   ONE micro-fix vs R14: L0's wave 0 (the poller) defers its 4 XP loads to
//   after barrier A (they hide under the h bulk-load ramp); waves 1-3 keep
//   the early prefetch. Everything else byte-identical to R14.
// Sequential grid-sync epochs: 256.
// ---------------------------------------------------------------------------

typedef __attribute__((ext_vector_type(8))) __bf16 bf16x8;
typedef __attribute__((ext_vector_type(4))) __bf16 bf16x4;
typedef __attribute__((ext_vector_type(4))) float  f32x4;

#define SLAB 32768   // bf16 elems per h slab: [128 j][32 b][8 col] = 64KB
// LDS: Wxh slice 64KB + Whh slice 64KB + sP (256 bf16)
#define RNN_SMEM (65536 + 65536 + 512)

__device__ __forceinline__ float sigmoidf_(float x) {
  return 1.f / (1.f + __expf(-x));
}
__device__ __forceinline__ float tanhf_(float x) {
  float e = __expf(-2.f * fabsf(x));
  float t = (1.f - e) / (1.f + e);
  return x < 0.f ? -t : t;
}

// ---------------------------------------------------------------------------
__global__ void init_ws(float* zeros, unsigned* flags) {
  int i = blockIdx.x * 256 + threadIdx.x;
  if (i < 32 * 1024) zeros[i] = 0.f;
  if (i < 512) flags[i] = 0u;          // 4 layers x 128 packed flags
}

// ---------------------------------------------------------------------------
__global__ void gather_emb(const int* __restrict__ src, const int* __restrict__ tgt,
                           const float* __restrict__ ee, const float* __restrict__ de,
                           __bf16* __restrict__ Xe, __bf16* __restrict__ Xd) {
  int row = blockIdx.x & 4095;
  int t = row >> 5, b = row & 31;
  bool isd = blockIdx.x >= 4096;
  int tok = isd ? (t == 0 ? 1 : tgt[b * 128 + t - 1]) : src[b * 128 + t];
  const float* ep = (isd ? de : ee) + (size_t)tok * 512;
  __bf16* op = (isd ? Xd : Xe) + (size_t)row * 512;
  int i = threadIdx.x * 4;
  float4 v = *(const float4*)(ep + i);
  bf16x4 t4;
  t4[0] = (__bf16)v.x; t4[1] = (__bf16)v.y; t4[2] = (__bf16)v.z; t4[3] = (__bf16)v.w;
  *(bf16x4*)(op + i) = t4;
}

// ---------------------------------------------------------------------------
// XP = A[M=4096,K=512](bf16) @ W[4096,K]^T(f32->bf16) + bih + bhh  (bf16 out)
// Output layout: XP[t][blk][hl][g][b]  (t=row>>5, b=row&31, col=g*1024+blk*8+hl)
__global__ __launch_bounds__(256) void gemm_xp(
    const __bf16* __restrict__ A, const float* __restrict__ W,
    const float* __restrict__ bih, const float* __restrict__ bhh,
    __bf16* __restrict__ C, int K) {
  __shared__ char sA[128 * 64 * 2];
  __shared__ char sB[128 * 64 * 2];
  int tid = threadIdx.x;
  int lane = tid & 63, wave = tid >> 6;
  int wm = wave & 1, wn = wave >> 1;
  int bm = blockIdx.x & 31, bn = blockIdx.x >> 5;
  int frow = lane & 15;
  int kj = (lane >> 4) * 16;

  f32x4 acc[4][4] = {};

  for (int k0 = 0; k0 < K; k0 += 64) {
#pragma unroll
    for (int c4 = 0; c4 < 4; ++c4) {   // stage A tile (bf16, swizzled)
      int idx = (c4 * 256 + tid) * 8;
      int r = idx >> 6, kk = idx & 63;
      bf16x8 v = *(const bf16x8*)(A + (size_t)(bm * 128 + r) * K + k0 + kk);
      *(bf16x8*)(sA + ((r * 128 + kk * 2) ^ ((r & 7) << 4))) = v;
    }
#pragma unroll
    for (int c4 = 0; c4 < 4; ++c4) {   // stage B tile (f32 -> bf16, swizzled)
      int idx = (c4 * 256 + tid) * 8;
      int r = idx >> 6, kk = idx & 63;
      const float* wp = W + (size_t)(bn * 128 + r) * K + k0 + kk;
      float4 w0 = *(const float4*)wp;
      float4 w1 = *(const float4*)(wp + 4);
      bf16x8 v;
      v[0] = (__bf16)w0.x; v[1] = (__bf16)w0.y; v[2] = (__bf16)w0.z; v[3] = (__bf16)w0.w;
      v[4] = (__bf16)w1.x; v[5] = (__bf16)w1.y; v[6] = (__bf16)w1.z; v[7] = (__bf16)w1.w;
      *(bf16x8*)(sB + ((r * 128 + kk * 2) ^ ((r & 7) << 4))) = v;
    }
    __syncthreads();
#pragma unroll
    for (int half = 0; half < 2; ++half) {
      int kb = half * 64 + kj;
      bf16x8 af[4], bfr[4];
#pragma unroll
      for (int f = 0; f < 4; ++f) {
        int arr = wm * 64 + f * 16 + frow;
        af[f] = *(const bf16x8*)(sA + (arr * 128 + (kb ^ ((arr & 7) << 4))));
        int brr = wn * 64 + f * 16 + frow;
        bfr[f] = *(const bf16x8*)(sB + (brr * 128 + (kb ^ ((brr & 7) << 4))));
      }
#pragma unroll
      for (int fm = 0; fm < 4; ++fm)
#pragma unroll
        for (int fn = 0; fn < 4; ++fn)
          acc[fm][fn] = __builtin_amdgcn_mfma_f32_16x16x32_bf16(af[fm], bfr[fn],
                                                                acc[fm][fn], 0, 0, 0);
    }
    __syncthreads();
  }
  int cm = bm * 128 + wm * 64, cn = bn * 128 + wn * 64;
#pragma unroll
  for (int fn = 0; fn < 4; ++fn) {
    int col = cn + fn * 16 + frow;
    int g = col >> 10, hcol = col & 1023;
    int blkd = hcol >> 3, hl = hcol & 7;
    float bias = bih[col] + bhh[col];
#pragma unroll
    for (int fm = 0; fm < 4; ++fm) {
      int r0 = cm + fm * 16 + ((lane >> 4) << 2);
#pragma unroll
      for (int j = 0; j < 4; ++j) {
        int row = r0 + j;
        // XP[t][blk][hl][g][b]
        C[(size_t)(row >> 5) * 131072 + blkd * 1024 + hl * 128 + g * 32 +
          (row & 31)] = (__bf16)(acc[fm][fn][j] + bias);
      }
    }
  }
}

// ---------------------------------------------------------------------------
struct RnnArgs {
  const float* Whh;       // [4096,1024] recurrent weights (f32)
  const float* Wxh;       // layer1: [4096,1024] input weights; layer0: nullptr
  const float* bih;       // layer1 bias (layer0: baked into XP)
  const float* bhh;
  const __bf16* XP;       // layer0: [t][blk][hl][g][b] bf16; layer1: nullptr
  const __bf16* xslab;    // layer1: [128][SLAB] lower layer's h slabs
  const unsigned* xflags; // layer1: lower layer's flags
  const __bf16* h0;       // [SLAB] initial h (slab layout)
  const float* c0;        // [32*1024] initial c
  __bf16* hseq;           // [128][SLAB]
  float* cfin;            // [32*1024]
  float* yout;            // nullptr or [B,T,H] f32
  unsigned* flags;        // [128] own produce flags (packed)
};

// Wave-0 poll: all 128 entries of fl >= t (lane covers fl[lane], fl[64+lane]).
__device__ __forceinline__ void wait128(const unsigned* fl, unsigned t) {
  int lane = threadIdx.x & 63;
  for (;;) {
    bool ok = (__hip_atomic_load(fl + lane, __ATOMIC_RELAXED,
                                 __HIP_MEMORY_SCOPE_AGENT) >= t) &&
              (__hip_atomic_load(fl + 64 + lane, __ATOMIC_RELAXED,
                                 __HIP_MEMORY_SCOPE_AGENT) >= t);
    if (__all(ok)) return;
    __builtin_amdgcn_s_sleep(1);
  }
}

// K=1024 accumulate, swapped operands, FULL-HOIST (R14 champion): all 32
// B-frag slab loads issue before the MFMA chain. A (weights) from LDS row.
__device__ __forceinline__ f32x4 accum_k1024_deep(f32x4 acc, const char* bbase,
                                                  const char* aRow, int swz,
                                                  int kj) {
  bf16x8 bv[32];
#pragma unroll
  for (int u = 0; u < 32; ++u)
    bv[u] = *(const bf16x8*)(bbase + (size_t)u * 2048);
#pragma unroll
  for (int u = 0; u < 32; ++u) {
    int kb = u * 64 + kj;
    bf16x8 av = *(const bf16x8*)(aRow + (kb ^ swz));
    acc = __builtin_amdgcn_mfma_f32_16x16x32_bf16(av, bv[u], acc, 0, 0, 0);
  }
  return acc;
}

__device__ __forceinline__ void rnn_body(const RnnArgs& P, int blk, char* smem) {
  char*   sW0 = smem;                              // Wxh slice (layer1)
  char*   sW1 = smem + 65536;                      // Whh slice
  __bf16* sP  = (__bf16*)(smem + 131072);          // [256] publish repack

  int tid = threadIdx.x;
  int lane = tid & 63, wave = tid >> 6;
  int mt = wave & 1, nt = wave >> 1;
  bool isL0 = (P.XP != nullptr);

  // one-time invalidate: kill stale L1/L2 lines from previous graph replays
  __builtin_amdgcn_fence(__ATOMIC_ACQUIRE, "agent");

  // ---- stage weight slices once, rows HL-MAJOR (lds row = hl*4 + gate)
  {
    const float* srcs[2] = {P.Wxh, P.Whh};
    char* dsts[2] = {sW0, sW1};
    for (int s = (isL0 ? 1 : 0); s < 2; ++s) {
      for (int g = 0; g < 4; ++g) {
        const float* sp = srcs[s] + (size_t)(g * 1024 + blk * 8) * 1024;
#pragma unroll
        for (int it = 0; it < 8; ++it) {
          int e = (it * 256 + tid) * 4;
          int rl = e >> 10, k = e & 1023;
          float4 v = *(const float4*)(sp + e);
          bf16x4 t4;
          t4[0] = (__bf16)v.x; t4[1] = (__bf16)v.y;
          t4[2] = (__bf16)v.z; t4[3] = (__bf16)v.w;
          int r = rl * 4 + g;   // hl-major
          *(bf16x4*)(dsts[s] + ((r << 11) + ((k << 1) ^ ((r & 7) << 4)))) = t4;
        }
      }
    }
  }

  // ---- cell ownership (swapped-MFMA C layout, verified R8/R10-R14):
  // lane -> hl = mt*4 + (lane>>4), b = nt*16 + (lane&15); acc[0..3]=i,f,g,o
  int hl = mt * 4 + (lane >> 4);
  int b  = nt * 16 + (lane & 15);
  float c = P.c0[b * 1024 + blk * 8 + hl];

  // layer1: per-thread gate biases (layer0 has them baked into XP)
  float bI = 0.f, bF = 0.f, bG = 0.f, bO = 0.f;
  if (!isL0) {
    int col = blk * 8 + hl;
    bI = P.bih[col] + P.bhh[col];
    bF = P.bih[1024 + col] + P.bhh[1024 + col];
    bG = P.bih[2048 + col] + P.bhh[2048 + col];
    bO = P.bih[3072 + col] + P.bhh[3072 + col];
  }

  int rr  = mt * 16 + (lane & 15);       // A (weight) row within 32-row slice
  int swz = (rr & 7) << 4;
  const char* aRow0 = sW0 + (rr << 11);
  const char* aRow1 = sW1 + (rr << 11);
  int kj   = (lane >> 4) * 16;           // A k-byte offset
  int bsub = (lane >> 4) * 512 + b * 16; // B (h) slab sub-offset

  if (isL0) {
    // =======================================================================
    // L0 path: R14 champion; micro-fix: wave 0 (the poller) defers its XP
    // loads to after barrier A so its flag-poll loads are never queued
    // behind them (per-wave in-order VMEM returns -- R15 lesson).
    // =======================================================================
    const __bf16* xpb = P.XP + (size_t)blk * 1024 + hl * 128 + b;
    for (int t = 0; t < 128; ++t) {
      const __bf16* xr = xpb + (size_t)t * 131072;
      float xi = 0.f, xf = 0.f, xg = 0.f, xo = 0.f;
      if (wave != 0) {   // early prefetch (hides under wave0's poll)
        xi = (float)xr[0];  xf = (float)xr[32];
        xg = (float)xr[64]; xo = (float)xr[96];
      }

      const char* hb = (const char*)((t == 0) ? P.h0
                         : (P.hseq + (size_t)(t - 1) * SLAB)) + bsub;
      f32x4 acc = {0.f, 0.f, 0.f, 0.f};

      if (wave == 0 && t > 0) wait128(P.flags, (unsigned)t);
      __syncthreads();
      if (wave == 0) {   // deferred XP load: hides under the h-load ramp
        xi = (float)xr[0];  xf = (float)xr[32];
        xg = (float)xr[64]; xo = (float)xr[96];
      }
      acc = accum_k1024_deep(acc, hb, aRow1, swz, kj);

      float gi = sigmoidf_(acc[0] + xi);
      float gf = sigmoidf_(acc[1] + xf);
      float gg = tanhf_(acc[2] + xg);
      float go = sigmoidf_(acc[3] + xo);
      c = gf * c + gi * gg;
      float h = go * tanhf_(c);
      sP[b * 8 + hl] = (__bf16)h;
      __syncthreads();

      if (tid < 64) {
        unsigned long long v = *(const unsigned long long*)(sP + tid * 4);
        unsigned long long* dst = (unsigned long long*)(
            (char*)P.hseq + (size_t)t * 65536 + blk * 512 + tid * 8);
        __hip_atomic_store(dst, v, __ATOMIC_RELAXED, __HIP_MEMORY_SCOPE_AGENT);
        asm volatile("s_waitcnt vmcnt(0)" ::: "memory");
        if (tid == 0)
          __hip_atomic_store(P.flags + blk, (unsigned)(t + 1), __ATOMIC_RELEASE,
                             __HIP_MEMORY_SCOPE_AGENT);
      }
    }
  } else {
    // =======================================================================
    // L1 path: byte-identical to R14 champion (two-phase x-first; own-h
    // flag propagation hides behind the x accumulation).
    // =======================================================================
    for (int t = 0; t < 128; ++t) {
      const char* hb = (const char*)((t == 0) ? P.h0
                         : (P.hseq + (size_t)(t - 1) * SLAB)) + bsub;
      f32x4 acc = {0.f, 0.f, 0.f, 0.f};

      if (wave == 0) wait128(P.xflags, (unsigned)(t + 1));
      __syncthreads();
      const char* xb = (const char*)(P.xslab + (size_t)t * SLAB) + bsub;
      acc = accum_k1024_deep(acc, xb, aRow0, swz, kj);
      if (wave == 0 && t > 0) wait128(P.flags, (unsigned)t);
      __syncthreads();
      acc = accum_k1024_deep(acc, hb, aRow1, swz, kj);

      // pointwise LSTM cell, fully in registers (acc = i,f,g,o)
      float gi = sigmoidf_(acc[0] + bI);
      float gf = sigmoidf_(acc[1] + bF);
      float gg = tanhf_(acc[2] + bG);
      float go = sigmoidf_(acc[3] + bO);
      c = gf * c + gi * gg;
      float h = go * tanhf_(c);
      sP[b * 8 + hl] = (__bf16)h;
      __syncthreads();

      // publish (champion): wave 0 only -- stores, OWN drain, flag release
      if (tid < 64) {
        unsigned long long v = *(const unsigned long long*)(sP + tid * 4);
        unsigned long long* dst = (unsigned long long*)(
            (char*)P.hseq + (size_t)t * 65536 + blk * 512 + tid * 8);
        __hip_atomic_store(dst, v, __ATOMIC_RELAXED, __HIP_MEMORY_SCOPE_AGENT);
        asm volatile("s_waitcnt vmcnt(0)" ::: "memory");
        if (tid == 0)
          __hip_atomic_store(P.flags + blk, (unsigned)(t + 1), __ATOMIC_RELEASE,
                             __HIP_MEMORY_SCOPE_AGENT);
      }
      // yout (final decoder layer only): coalesced from sP
      if (P.yout) {
        int yb = tid >> 3, yhl = tid & 7;
        P.yout[((size_t)yb * 128 + t) * 1024 + blk * 8 + yhl] =
            (float)sP[yb * 8 + yhl];
      }
    }
  }
  P.cfin[b * 1024 + blk * 8 + hl] = c;
}

// Blocks 0-127: layer0 (A). Blocks 128-255: layer1 (B), 1-step skewed.
__global__ __launch_bounds__(256, 1) void rnn_pair(RnnArgs A, RnnArgs B) {
  extern __shared__ char smem[];
  if (blockIdx.x < 128) rnn_body(A, blockIdx.x, smem);
  else                  rnn_body(B, blockIdx.x - 128, smem);
}

// ---------------------------------------------------------------------------
extern "C" void kernel_launch(void* const* d_in, const int* in_sizes, int n_in,
                              void* d_out, int out_size, void* d_ws, size_t ws_size,
                              hipStream_t stream) {
  (void)in_sizes; (void)n_in; (void)out_size; (void)ws_size;
  const int*   src     = (const int*)d_in[0];
  const int*   tgt     = (const int*)d_in[1];
  const float* enc_emb = (const float*)d_in[2];
  const float* dec_emb = (const float*)d_in[3];
  const float* W[16];
  for (int i = 0; i < 16; ++i) W[i] = (const float*)d_in[4 + i];
  // enc: Wih0=W[0] Whh0=W[1] bih0=W[2] bhh0=W[3]  Wih1=W[4] Whh1=W[5] b=W[6],W[7]
  // dec: Wih0=W[8] Whh0=W[9] b=W[10],W[11]        Wih1=W[12] Whh1=W[13] b=W[14],W[15]

  char* ws = (char*)d_ws;
  size_t off = 0;
  auto alloc = [&](size_t bytes) {
    char* p = ws + off;
    off += (bytes + 255) & ~(size_t)255;
    return p;
  };
  unsigned* flags = (unsigned*)alloc((size_t)4 * 128 * sizeof(unsigned));
  float*    zeros = (float*)alloc((size_t)32 * 1024 * 4);
  __bf16*   Xe   = (__bf16*)alloc((size_t)4096 * 512 * 2);
  __bf16*   Xd   = (__bf16*)alloc((size_t)4096 * 512 * 2);
  __bf16*   XP1  = (__bf16*)alloc((size_t)4096 * 4096 * 2);
  __bf16*   XP2  = (__bf16*)alloc((size_t)4096 * 4096 * 2);
  __bf16*   hE0  = (__bf16*)alloc((size_t)128 * SLAB * 2);
  __bf16*   hE1  = (__bf16*)alloc((size_t)128 * SLAB * 2);
  __bf16*   hD0  = (__bf16*)alloc((size_t)128 * SLAB * 2);
  __bf16*   hD1  = (__bf16*)alloc((size_t)128 * SLAB * 2);
  float*    cE0  = (float*)alloc((size_t)32 * 1024 * 4);
  float*    cE1  = (float*)alloc((size_t)32 * 1024 * 4);
  float*    cd0  = (float*)alloc((size_t)32 * 1024 * 4);
  float*    cd1  = (float*)alloc((size_t)32 * 1024 * 4);

  hipFuncSetAttribute((const void*)rnn_pair,
                      hipFuncAttributeMaxDynamicSharedMemorySize, RNN_SMEM);

  init_ws<<<128, 256, 0, stream>>>(zeros, flags);
  gather_emb<<<8192, 128, 0, stream>>>(src, tgt, enc_emb, dec_emb, Xe, Xd);

  // layer-0 x-parts (K=512) for both encoder and decoder, up front
  gemm_xp<<<1024, 256, 0, stream>>>(Xe, W[0], W[2], W[3], XP1, 512);
  gemm_xp<<<1024, 256, 0, stream>>>(Xd, W[8], W[10], W[11], XP2, 512);

  unsigned* fE0 = flags;
  unsigned* fE1 = flags + 128;
  unsigned* fD0 = flags + 256;
  unsigned* fD1 = flags + 384;

  // encoder epoch: L0 (blocks 0-127) + L1 skewed (blocks 128-255)
  RnnArgs e0{W[1], nullptr, nullptr, nullptr, XP1, nullptr, nullptr,
             (const __bf16*)zeros, zeros, hE0, cE0, nullptr, fE0};
  RnnArgs e1{W[5], W[4], W[6], W[7], nullptr, hE0, fE0,
             (const __bf16*)zeros, zeros, hE1, cE1, nullptr, fE1};
  rnn_pair<<<256, 256, RNN_SMEM, stream>>>(e0, e1);

  // decoder epoch: L0 init = encL0 finals, L1 init = encL1 finals -> d_out
  RnnArgs d0{W[9], nullptr, nullptr, nullptr, XP2, nullptr, nullptr,
             hE0 + (size_t)127 * SLAB, cE0, hD0, cd0, nullptr, fD0};
  RnnArgs d1{W[13], W[12], W[14], W[15], nullptr, hD0, fD0,
             hE1 + (size_t)127 * SLAB, cE1, hD1, cd1, (float*)d_out, fD1};
  rnn_pair<<<256, 256, RNN_SMEM, stream>>>(d0, d1);
}

// Round 18
// 1793.115 us; speedup vs baseline: 1.4526x; 1.2877x over previous
//
#include <hip/hip_runtime.h>
#include <hip/hip_bf16.h>
#include <stdint.h>

// ---------------------------------------------------------------------------
// Seq2seq LSTM (2-layer enc + 2-layer dec, B=32, S=T=128, E=512, H=1024).
//   gather_emb -> bf16 X
//   gemm_xp: XP = X @ Wih0^T + bias, bf16, layout [t][blk][hl][g][b]
//   rnn_pair: ONE dispatch per enc/dec, 256 blocks, layer0 + layer1 skewed.
//   == EXACT RESUBMISSION OF THE R14 CHAMPION (measured 1799us total) ==
//   R12 champion protocol (two-phase x-first L1, single-poll L0, wave0-only
//   publish) + full-hoist accumulation (all 32 slab loads before the MFMA
//   chain). Serves as both champion-restore and cross-round reproducibility
//   probe (R15/R17 landed ~1150us/dispatch with very different kernels).
// Sequential grid-sync epochs: 256.
// ---------------------------------------------------------------------------

typedef __attribute__((ext_vector_type(8))) __bf16 bf16x8;
typedef __attribute__((ext_vector_type(4))) __bf16 bf16x4;
typedef __attribute__((ext_vector_type(4))) float  f32x4;

#define SLAB 32768   // bf16 elems per h slab: [128 j][32 b][8 col] = 64KB
// LDS: Wxh slice 64KB + Whh slice 64KB + sP (256 bf16)
#define RNN_SMEM (65536 + 65536 + 512)

__device__ __forceinline__ float sigmoidf_(float x) {
  return 1.f / (1.f + __expf(-x));
}
__device__ __forceinline__ float tanhf_(float x) {
  float e = __expf(-2.f * fabsf(x));
  float t = (1.f - e) / (1.f + e);
  return x < 0.f ? -t : t;
}

// ---------------------------------------------------------------------------
__global__ void init_ws(float* zeros, unsigned* flags) {
  int i = blockIdx.x * 256 + threadIdx.x;
  if (i < 32 * 1024) zeros[i] = 0.f;
  if (i < 512) flags[i] = 0u;          // 4 layers x 128 packed flags
}

// ---------------------------------------------------------------------------
__global__ void gather_emb(const int* __restrict__ src, const int* __restrict__ tgt,
                           const float* __restrict__ ee, const float* __restrict__ de,
                           __bf16* __restrict__ Xe, __bf16* __restrict__ Xd) {
  int row = blockIdx.x & 4095;
  int t = row >> 5, b = row & 31;
  bool isd = blockIdx.x >= 4096;
  int tok = isd ? (t == 0 ? 1 : tgt[b * 128 + t - 1]) : src[b * 128 + t];
  const float* ep = (isd ? de : ee) + (size_t)tok * 512;
  __bf16* op = (isd ? Xd : Xe) + (size_t)row * 512;
  int i = threadIdx.x * 4;
  float4 v = *(const float4*)(ep + i);
  bf16x4 t4;
  t4[0] = (__bf16)v.x; t4[1] = (__bf16)v.y; t4[2] = (__bf16)v.z; t4[3] = (__bf16)v.w;
  *(bf16x4*)(op + i) = t4;
}

// ---------------------------------------------------------------------------
// XP = A[M=4096,K=512](bf16) @ W[4096,K]^T(f32->bf16) + bih + bhh  (bf16 out)
// Output layout: XP[t][blk][hl][g][b]  (t=row>>5, b=row&31, col=g*1024+blk*8+hl)
__global__ __launch_bounds__(256) void gemm_xp(
    const __bf16* __restrict__ A, const float* __restrict__ W,
    const float* __restrict__ bih, const float* __restrict__ bhh,
    __bf16* __restrict__ C, int K) {
  __shared__ char sA[128 * 64 * 2];
  __shared__ char sB[128 * 64 * 2];
  int tid = threadIdx.x;
  int lane = tid & 63, wave = tid >> 6;
  int wm = wave & 1, wn = wave >> 1;
  int bm = blockIdx.x & 31, bn = blockIdx.x >> 5;
  int frow = lane & 15;
  int kj = (lane >> 4) * 16;

  f32x4 acc[4][4] = {};

  for (int k0 = 0; k0 < K; k0 += 64) {
#pragma unroll
    for (int c4 = 0; c4 < 4; ++c4) {   // stage A tile (bf16, swizzled)
      int idx = (c4 * 256 + tid) * 8;
      int r = idx >> 6, kk = idx & 63;
      bf16x8 v = *(const bf16x8*)(A + (size_t)(bm * 128 + r) * K + k0 + kk);
      *(bf16x8*)(sA + ((r * 128 + kk * 2) ^ ((r & 7) << 4))) = v;
    }
#pragma unroll
    for (int c4 = 0; c4 < 4; ++c4) {   // stage B tile (f32 -> bf16, swizzled)
      int idx = (c4 * 256 + tid) * 8;
      int r = idx >> 6, kk = idx & 63;
      const float* wp = W + (size_t)(bn * 128 + r) * K + k0 + kk;
      float4 w0 = *(const float4*)wp;
      float4 w1 = *(const float4*)(wp + 4);
      bf16x8 v;
      v[0] = (__bf16)w0.x; v[1] = (__bf16)w0.y; v[2] = (__bf16)w0.z; v[3] = (__bf16)w0.w;
      v[4] = (__bf16)w1.x; v[5] = (__bf16)w1.y; v[6] = (__bf16)w1.z; v[7] = (__bf16)w1.w;
      *(bf16x8*)(sB + ((r * 128 + kk * 2) ^ ((r & 7) << 4))) = v;
    }
    __syncthreads();
#pragma unroll
    for (int half = 0; half < 2; ++half) {
      int kb = half * 64 + kj;
      bf16x8 af[4], bfr[4];
#pragma unroll
      for (int f = 0; f < 4; ++f) {
        int arr = wm * 64 + f * 16 + frow;
        af[f] = *(const bf16x8*)(sA + (arr * 128 + (kb ^ ((arr & 7) << 4))));
        int brr = wn * 64 + f * 16 + frow;
        bfr[f] = *(const bf16x8*)(sB + (brr * 128 + (kb ^ ((brr & 7) << 4))));
      }
#pragma unroll
      for (int fm = 0; fm < 4; ++fm)
#pragma unroll
        for (int fn = 0; fn < 4; ++fn)
          acc[fm][fn] = __builtin_amdgcn_mfma_f32_16x16x32_bf16(af[fm], bfr[fn],
                                                                acc[fm][fn], 0, 0, 0);
    }
    __syncthreads();
  }
  int cm = bm * 128 + wm * 64, cn = bn * 128 + wn * 64;
#pragma unroll
  for (int fn = 0; fn < 4; ++fn) {
    int col = cn + fn * 16 + frow;
    int g = col >> 10, hcol = col & 1023;
    int blkd = hcol >> 3, hl = hcol & 7;
    float bias = bih[col] + bhh[col];
#pragma unroll
    for (int fm = 0; fm < 4; ++fm) {
      int r0 = cm + fm * 16 + ((lane >> 4) << 2);
#pragma unroll
      for (int j = 0; j < 4; ++j) {
        int row = r0 + j;
        // XP[t][blk][hl][g][b]
        C[(size_t)(row >> 5) * 131072 + blkd * 1024 + hl * 128 + g * 32 +
          (row & 31)] = (__bf16)(acc[fm][fn][j] + bias);
      }
    }
  }
}

// ---------------------------------------------------------------------------
struct RnnArgs {
  const float* Whh;       // [4096,1024] recurrent weights (f32)
  const float* Wxh;       // layer1: [4096,1024] input weights; layer0: nullptr
  const float* bih;       // layer1 bias (layer0: baked into XP)
  const float* bhh;
  const __bf16* XP;       // layer0: [t][blk][hl][g][b] bf16; layer1: nullptr
  const __bf16* xslab;    // layer1: [128][SLAB] lower layer's h slabs
  const unsigned* xflags; // layer1: lower layer's flags
  const __bf16* h0;       // [SLAB] initial h (slab layout)
  const float* c0;        // [32*1024] initial c
  __bf16* hseq;           // [128][SLAB]
  float* cfin;            // [32*1024]
  float* yout;            // nullptr or [B,T,H] f32
  unsigned* flags;        // [128] own produce flags (packed)
};

// Wave-0 poll: all 128 entries of fl >= t (lane covers fl[lane], fl[64+lane]).
__device__ __forceinline__ void wait128(const unsigned* fl, unsigned t) {
  int lane = threadIdx.x & 63;
  for (;;) {
    bool ok = (__hip_atomic_load(fl + lane, __ATOMIC_RELAXED,
                                 __HIP_MEMORY_SCOPE_AGENT) >= t) &&
              (__hip_atomic_load(fl + 64 + lane, __ATOMIC_RELAXED,
                                 __HIP_MEMORY_SCOPE_AGENT) >= t);
    if (__all(ok)) return;
    __builtin_amdgcn_s_sleep(1);
  }
}

// K=1024 accumulate, swapped operands, FULL-HOIST (R14 champion): all 32
// B-frag slab loads issue before the MFMA chain. A (weights) from LDS row.
__device__ __forceinline__ f32x4 accum_k1024_deep(f32x4 acc, const char* bbase,
                                                  const char* aRow, int swz,
                                                  int kj) {
  bf16x8 bv[32];
#pragma unroll
  for (int u = 0; u < 32; ++u)
    bv[u] = *(const bf16x8*)(bbase + (size_t)u * 2048);
#pragma unroll
  for (int u = 0; u < 32; ++u) {
    int kb = u * 64 + kj;
    bf16x8 av = *(const bf16x8*)(aRow + (kb ^ swz));
    acc = __builtin_amdgcn_mfma_f32_16x16x32_bf16(av, bv[u], acc, 0, 0, 0);
  }
  return acc;
}

__device__ __forceinline__ void rnn_body(const RnnArgs& P, int blk, char* smem) {
  char*   sW0 = smem;                              // Wxh slice (layer1)
  char*   sW1 = smem + 65536;                      // Whh slice
  __bf16* sP  = (__bf16*)(smem + 131072);          // [256] publish repack

  int tid = threadIdx.x;
  int lane = tid & 63, wave = tid >> 6;
  int mt = wave & 1, nt = wave >> 1;
  bool isL0 = (P.XP != nullptr);

  // one-time invalidate: kill stale L1/L2 lines from previous graph replays
  __builtin_amdgcn_fence(__ATOMIC_ACQUIRE, "agent");

  // ---- stage weight slices once, rows HL-MAJOR (lds row = hl*4 + gate)
  {
    const float* srcs[2] = {P.Wxh, P.Whh};
    char* dsts[2] = {sW0, sW1};
    for (int s = (isL0 ? 1 : 0); s < 2; ++s) {
      for (int g = 0; g < 4; ++g) {
        const float* sp = srcs[s] + (size_t)(g * 1024 + blk * 8) * 1024;
#pragma unroll
        for (int it = 0; it < 8; ++it) {
          int e = (it * 256 + tid) * 4;
          int rl = e >> 10, k = e & 1023;
          float4 v = *(const float4*)(sp + e);
          bf16x4 t4;
          t4[0] = (__bf16)v.x; t4[1] = (__bf16)v.y;
          t4[2] = (__bf16)v.z; t4[3] = (__bf16)v.w;
          int r = rl * 4 + g;   // hl-major
          *(bf16x4*)(dsts[s] + ((r << 11) + ((k << 1) ^ ((r & 7) << 4)))) = t4;
        }
      }
    }
  }

  // ---- cell ownership (swapped-MFMA C layout, verified R8/R10-R14):
  // lane -> hl = mt*4 + (lane>>4), b = nt*16 + (lane&15); acc[0..3]=i,f,g,o
  int hl = mt * 4 + (lane >> 4);
  int b  = nt * 16 + (lane & 15);
  float c = P.c0[b * 1024 + blk * 8 + hl];

  // layer1: per-thread gate biases (layer0 has them baked into XP)
  float bI = 0.f, bF = 0.f, bG = 0.f, bO = 0.f;
  if (!isL0) {
    int col = blk * 8 + hl;
    bI = P.bih[col] + P.bhh[col];
    bF = P.bih[1024 + col] + P.bhh[1024 + col];
    bG = P.bih[2048 + col] + P.bhh[2048 + col];
    bO = P.bih[3072 + col] + P.bhh[3072 + col];
  }

  int rr  = mt * 16 + (lane & 15);       // A (weight) row within 32-row slice
  int swz = (rr & 7) << 4;
  const char* aRow0 = sW0 + (rr << 11);
  const char* aRow1 = sW1 + (rr << 11);
  int kj   = (lane >> 4) * 16;           // A k-byte offset
  int bsub = (lane >> 4) * 512 + b * 16; // B (h) slab sub-offset

  // XP prefetch base (coalesced: [t][blk][hl][g][b], b = lane-contiguous)
  const __bf16* xpb = isL0 ? (P.XP + (size_t)blk * 1024 + hl * 128 + b) : nullptr;

  for (int t = 0; t < 128; ++t) {
    float xi = bI, xf = bF, xg = bG, xo = bO;
    if (isL0) {   // prefetch XP operands before the poll (in flight during it)
      const __bf16* xr = xpb + (size_t)t * 131072;
      xi = (float)xr[0];  xf = (float)xr[32];
      xg = (float)xr[64]; xo = (float)xr[96];
    }

    const char* hb = (const char*)((t == 0) ? P.h0
                                            : (P.hseq + (size_t)(t - 1) * SLAB)) + bsub;
    f32x4 acc = {0.f, 0.f, 0.f, 0.f};

    if (isL0) {
      // single poll (champion): own h_{t-1} from all 128 L0 blocks
      if (wave == 0 && t > 0) wait128(P.flags, (unsigned)t);
      __syncthreads();
      acc = accum_k1024_deep(acc, hb, aRow1, swz, kj);
    } else {
      // two-phase: x first (L0 runs ahead -> poll returns immediately),
      // own-h flag propagation hides behind the x accumulation.
      if (wave == 0) wait128(P.xflags, (unsigned)(t + 1));
      __syncthreads();
      const char* xb = (const char*)(P.xslab + (size_t)t * SLAB) + bsub;
      acc = accum_k1024_deep(acc, xb, aRow0, swz, kj);
      if (wave == 0 && t > 0) wait128(P.flags, (unsigned)t);
      __syncthreads();
      acc = accum_k1024_deep(acc, hb, aRow1, swz, kj);
    }

    // ---- pointwise LSTM cell, fully in registers (acc = i,f,g,o)
    float gi = sigmoidf_(acc[0] + xi);
    float gf = sigmoidf_(acc[1] + xf);
    float gg = tanhf_(acc[2] + xg);
    float go = sigmoidf_(acc[3] + xo);
    c = gf * c + gi * gg;
    float h = go * tanhf_(c);
    sP[b * 8 + hl] = (__bf16)h;    // repack [32 b][8 hl]
    __syncthreads();

    // ---- publish (champion): wave 0 only -- stores, OWN drain, flag.
    //      No trailing barrier; waves 1-3 run ahead.
    if (tid < 64) {
      unsigned long long v = *(const unsigned long long*)(sP + tid * 4);
      unsigned long long* dst = (unsigned long long*)(
          (char*)P.hseq + (size_t)t * 65536 + blk * 512 + tid * 8);
      __hip_atomic_store(dst, v, __ATOMIC_RELAXED, __HIP_MEMORY_SCOPE_AGENT);
      asm volatile("s_waitcnt vmcnt(0)" ::: "memory");
      if (tid == 0)
        __hip_atomic_store(P.flags + blk, (unsigned)(t + 1), __ATOMIC_RELEASE,
                           __HIP_MEMORY_SCOPE_AGENT);
    }
    // ---- yout (final decoder layer only): coalesced from sP
    if (P.yout) {
      int yb = tid >> 3, yhl = tid & 7;
      P.yout[((size_t)yb * 128 + t) * 1024 + blk * 8 + yhl] =
          (float)sP[yb * 8 + yhl];
    }
  }
  P.cfin[b * 1024 + blk * 8 + hl] = c;
}

// Blocks 0-127: layer0 (A). Blocks 128-255: layer1 (B), 1-step skewed.
__global__ __launch_bounds__(256, 1) void rnn_pair(RnnArgs A, RnnArgs B) {
  extern __shared__ char smem[];
  if (blockIdx.x < 128) rnn_body(A, blockIdx.x, smem);
  else                  rnn_body(B, blockIdx.x - 128, smem);
}

// ---------------------------------------------------------------------------
extern "C" void kernel_launch(void* const* d_in, const int* in_sizes, int n_in,
                              void* d_out, int out_size, void* d_ws, size_t ws_size,
                              hipStream_t stream) {
  (void)in_sizes; (void)n_in; (void)out_size; (void)ws_size;
  const int*   src     = (const int*)d_in[0];
  const int*   tgt     = (const int*)d_in[1];
  const float* enc_emb = (const float*)d_in[2];
  const float* dec_emb = (const float*)d_in[3];
  const float* W[16];
  for (int i = 0; i < 16; ++i) W[i] = (const float*)d_in[4 + i];
  // enc: Wih0=W[0] Whh0=W[1] bih0=W[2] bhh0=W[3]  Wih1=W[4] Whh1=W[5] b=W[6],W[7]
  // dec: Wih0=W[8] Whh0=W[9] b=W[10],W[11]        Wih1=W[12] Whh1=W[13] b=W[14],W[15]

  char* ws = (char*)d_ws;
  size_t off = 0;
  auto alloc = [&](size_t bytes) {
    char* p = ws + off;
    off += (bytes + 255) & ~(size_t)255;
    return p;
  };
  unsigned* flags = (unsigned*)alloc((size_t)4 * 128 * sizeof(unsigned));
  float*    zeros = (float*)alloc((size_t)32 * 1024 * 4);
  __bf16*   Xe   = (__bf16*)alloc((size_t)4096 * 512 * 2);
  __bf16*   Xd   = (__bf16*)alloc((size_t)4096 * 512 * 2);
  __bf16*   XP1  = (__bf16*)alloc((size_t)4096 * 4096 * 2);
  __bf16*   XP2  = (__bf16*)alloc((size_t)4096 * 4096 * 2);
  __bf16*   hE0  = (__bf16*)alloc((size_t)128 * SLAB * 2);
  __bf16*   hE1  = (__bf16*)alloc((size_t)128 * SLAB * 2);
  __bf16*   hD0  = (__bf16*)alloc((size_t)128 * SLAB * 2);
  __bf16*   hD1  = (__bf16*)alloc((size_t)128 * SLAB * 2);
  float*    cE0  = (float*)alloc((size_t)32 * 1024 * 4);
  float*    cE1  = (float*)alloc((size_t)32 * 1024 * 4);
  float*    cd0  = (float*)alloc((size_t)32 * 1024 * 4);
  float*    cd1  = (float*)alloc((size_t)32 * 1024 * 4);

  hipFuncSetAttribute((const void*)rnn_pair,
                      hipFuncAttributeMaxDynamicSharedMemorySize, RNN_SMEM);

  init_ws<<<128, 256, 0, stream>>>(zeros, flags);
  gather_emb<<<8192, 128, 0, stream>>>(src, tgt, enc_emb, dec_emb, Xe, Xd);

  // layer-0 x-parts (K=512) for both encoder and decoder, up front
  gemm_xp<<<1024, 256, 0, stream>>>(Xe, W[0], W[2], W[3], XP1, 512);
  gemm_xp<<<1024, 256, 0, stream>>>(Xd, W[8], W[10], W[11], XP2, 512);

  unsigned* fE0 = flags;
  unsigned* fE1 = flags + 128;
  unsigned* fD0 = flags + 256;
  unsigned* fD1 = flags + 384;

  // encoder epoch: L0 (blocks 0-127) + L1 skewed (blocks 128-255)
  RnnArgs e0{W[1], nullptr, nullptr, nullptr, XP1, nullptr, nullptr,
             (const __bf16*)zeros, zeros, hE0, cE0, nullptr, fE0};
  RnnArgs e1{W[5], W[4], W[6], W[7], nullptr, hE0, fE0,
             (const __bf16*)zeros, zeros, hE1, cE1, nullptr, fE1};
  rnn_pair<<<256, 256, RNN_SMEM, stream>>>(e0, e1);

  // decoder epoch: L0 init = encL0 finals, L1 init = encL1 finals -> d_out
  RnnArgs d0{W[9], nullptr, nullptr, nullptr, XP2, nullptr, nullptr,
             hE0 + (size_t)127 * SLAB, cE0, hD0, cd0, nullptr, fD0};
  RnnArgs d1{W[13], W[12], W[14], W[15], nullptr, hD0, fD0,
             hE1 + (size_t)127 * SLAB, cE1, hD1, cd1, (float*)d_out, fD1};
  rnn_pair<<<256, 256, RNN_SMEM, stream>>>(d0, d1);
}

// Round 19
// 1767.635 us; speedup vs baseline: 1.4736x; 1.0144x over previous
//
#include <hip/hip_runtime.h>
#include <hip/hip_bf16.h>
#include <stdint.h>

// ---------------------------------------------------------------------------
// Seq2seq LSTM (2-layer enc + 2-layer dec, B=32, S=T=128, E=512, H=1024).
//   gather_emb -> bf16 X
//   gemm_xp: XP = X @ Wih0^T + bias, bf16, layout [t][blk][hl][g][b]
//   rnn_pair: ONE dispatch per enc/dec, 256 blocks, layer0 + layer1 skewed.
//   == R14/R18 champion (1793us, reproduced) ==
//   ONE change: wait128 polls via single b64 atomic loads (lane covers
//   flags[2l..2l+1] in one VMEM op, halving poll RTTs) + adaptive spin
//   (16 no-sleep iterations before s_sleep backoff). Everything else
//   byte-identical to R18.
// Sequential grid-sync epochs: 256.
// ---------------------------------------------------------------------------

typedef __attribute__((ext_vector_type(8))) __bf16 bf16x8;
typedef __attribute__((ext_vector_type(4))) __bf16 bf16x4;
typedef __attribute__((ext_vector_type(4))) float  f32x4;

#define SLAB 32768   // bf16 elems per h slab: [128 j][32 b][8 col] = 64KB
// LDS: Wxh slice 64KB + Whh slice 64KB + sP (256 bf16)
#define RNN_SMEM (65536 + 65536 + 512)

__device__ __forceinline__ float sigmoidf_(float x) {
  return 1.f / (1.f + __expf(-x));
}
__device__ __forceinline__ float tanhf_(float x) {
  float e = __expf(-2.f * fabsf(x));
  float t = (1.f - e) / (1.f + e);
  return x < 0.f ? -t : t;
}

// ---------------------------------------------------------------------------
__global__ void init_ws(float* zeros, unsigned* flags) {
  int i = blockIdx.x * 256 + threadIdx.x;
  if (i < 32 * 1024) zeros[i] = 0.f;
  if (i < 512) flags[i] = 0u;          // 4 layers x 128 packed flags
}

// ---------------------------------------------------------------------------
__global__ void gather_emb(const int* __restrict__ src, const int* __restrict__ tgt,
                           const float* __restrict__ ee, const float* __restrict__ de,
                           __bf16* __restrict__ Xe, __bf16* __restrict__ Xd) {
  int row = blockIdx.x & 4095;
  int t = row >> 5, b = row & 31;
  bool isd = blockIdx.x >= 4096;
  int tok = isd ? (t == 0 ? 1 : tgt[b * 128 + t - 1]) : src[b * 128 + t];
  const float* ep = (isd ? de : ee) + (size_t)tok * 512;
  __bf16* op = (isd ? Xd : Xe) + (size_t)row * 512;
  int i = threadIdx.x * 4;
  float4 v = *(const float4*)(ep + i);
  bf16x4 t4;
  t4[0] = (__bf16)v.x; t4[1] = (__bf16)v.y; t4[2] = (__bf16)v.z; t4[3] = (__bf16)v.w;
  *(bf16x4*)(op + i) = t4;
}

// ---------------------------------------------------------------------------
// XP = A[M=4096,K=512](bf16) @ W[4096,K]^T(f32->bf16) + bih + bhh  (bf16 out)
// Output layout: XP[t][blk][hl][g][b]  (t=row>>5, b=row&31, col=g*1024+blk*8+hl)
__global__ __launch_bounds__(256) void gemm_xp(
    const __bf16* __restrict__ A, const float* __restrict__ W,
    const float* __restrict__ bih, const float* __restrict__ bhh,
    __bf16* __restrict__ C, int K) {
  __shared__ char sA[128 * 64 * 2];
  __shared__ char sB[128 * 64 * 2];
  int tid = threadIdx.x;
  int lane = tid & 63, wave = tid >> 6;
  int wm = wave & 1, wn = wave >> 1;
  int bm = blockIdx.x & 31, bn = blockIdx.x >> 5;
  int frow = lane & 15;
  int kj = (lane >> 4) * 16;

  f32x4 acc[4][4] = {};

  for (int k0 = 0; k0 < K; k0 += 64) {
#pragma unroll
    for (int c4 = 0; c4 < 4; ++c4) {   // stage A tile (bf16, swizzled)
      int idx = (c4 * 256 + tid) * 8;
      int r = idx >> 6, kk = idx & 63;
      bf16x8 v = *(const bf16x8*)(A + (size_t)(bm * 128 + r) * K + k0 + kk);
      *(bf16x8*)(sA + ((r * 128 + kk * 2) ^ ((r & 7) << 4))) = v;
    }
#pragma unroll
    for (int c4 = 0; c4 < 4; ++c4) {   // stage B tile (f32 -> bf16, swizzled)
      int idx = (c4 * 256 + tid) * 8;
      int r = idx >> 6, kk = idx & 63;
      const float* wp = W + (size_t)(bn * 128 + r) * K + k0 + kk;
      float4 w0 = *(const float4*)wp;
      float4 w1 = *(const float4*)(wp + 4);
      bf16x8 v;
      v[0] = (__bf16)w0.x; v[1] = (__bf16)w0.y; v[2] = (__bf16)w0.z; v[3] = (__bf16)w0.w;
      v[4] = (__bf16)w1.x; v[5] = (__bf16)w1.y; v[6] = (__bf16)w1.z; v[7] = (__bf16)w1.w;
      *(bf16x8*)(sB + ((r * 128 + kk * 2) ^ ((r & 7) << 4))) = v;
    }
    __syncthreads();
#pragma unroll
    for (int half = 0; half < 2; ++half) {
      int kb = half * 64 + kj;
      bf16x8 af[4], bfr[4];
#pragma unroll
      for (int f = 0; f < 4; ++f) {
        int arr = wm * 64 + f * 16 + frow;
        af[f] = *(const bf16x8*)(sA + (arr * 128 + (kb ^ ((arr & 7) << 4))));
        int brr = wn * 64 + f * 16 + frow;
        bfr[f] = *(const bf16x8*)(sB + (brr * 128 + (kb ^ ((brr & 7) << 4))));
      }
#pragma unroll
      for (int fm = 0; fm < 4; ++fm)
#pragma unroll
        for (int fn = 0; fn < 4; ++fn)
          acc[fm][fn] = __builtin_amdgcn_mfma_f32_16x16x32_bf16(af[fm], bfr[fn],
                                                                acc[fm][fn], 0, 0, 0);
    }
    __syncthreads();
  }
  int cm = bm * 128 + wm * 64, cn = bn * 128 + wn * 64;
#pragma unroll
  for (int fn = 0; fn < 4; ++fn) {
    int col = cn + fn * 16 + frow;
    int g = col >> 10, hcol = col & 1023;
    int blkd = hcol >> 3, hl = hcol & 7;
    float bias = bih[col] + bhh[col];
#pragma unroll
    for (int fm = 0; fm < 4; ++fm) {
      int r0 = cm + fm * 16 + ((lane >> 4) << 2);
#pragma unroll
      for (int j = 0; j < 4; ++j) {
        int row = r0 + j;
        // XP[t][blk][hl][g][b]
        C[(size_t)(row >> 5) * 131072 + blkd * 1024 + hl * 128 + g * 32 +
          (row & 31)] = (__bf16)(acc[fm][fn][j] + bias);
      }
    }
  }
}

// ---------------------------------------------------------------------------
struct RnnArgs {
  const float* Whh;       // [4096,1024] recurrent weights (f32)
  const float* Wxh;       // layer1: [4096,1024] input weights; layer0: nullptr
  const float* bih;       // layer1 bias (layer0: baked into XP)
  const float* bhh;
  const __bf16* XP;       // layer0: [t][blk][hl][g][b] bf16; layer1: nullptr
  const __bf16* xslab;    // layer1: [128][SLAB] lower layer's h slabs
  const unsigned* xflags; // layer1: lower layer's flags
  const __bf16* h0;       // [SLAB] initial h (slab layout)
  const float* c0;        // [32*1024] initial c
  __bf16* hseq;           // [128][SLAB]
  float* cfin;            // [32*1024]
  float* yout;            // nullptr or [B,T,H] f32
  unsigned* flags;        // [128] own produce flags (packed)
};

// Wave-0 poll: all 128 flags >= t. ONE b64 atomic load per lane per
// iteration (flags[2l], flags[2l+1] share an 8B word); adaptive spin --
// 16 raw iterations before s_sleep backoff.
__device__ __forceinline__ void wait128(const unsigned* fl, unsigned t) {
  int lane = threadIdx.x & 63;
  const unsigned long long* p = (const unsigned long long*)fl + lane;
  int spins = 0;
  for (;;) {
    unsigned long long v = __hip_atomic_load(p, __ATOMIC_RELAXED,
                                             __HIP_MEMORY_SCOPE_AGENT);
    bool ok = ((unsigned)v >= t) && ((unsigned)(v >> 32) >= t);
    if (__all(ok)) return;
    if (++spins > 16) __builtin_amdgcn_s_sleep(1);
  }
}

// K=1024 accumulate, swapped operands, FULL-HOIST (champion): all 32
// B-frag slab loads issue before the MFMA chain. A (weights) from LDS row.
__device__ __forceinline__ f32x4 accum_k1024_deep(f32x4 acc, const char* bbase,
                                                  const char* aRow, int swz,
                                                  int kj) {
  bf16x8 bv[32];
#pragma unroll
  for (int u = 0; u < 32; ++u)
    bv[u] = *(const bf16x8*)(bbase + (size_t)u * 2048);
#pragma unroll
  for (int u = 0; u < 32; ++u) {
    int kb = u * 64 + kj;
    bf16x8 av = *(const bf16x8*)(aRow + (kb ^ swz));
    acc = __builtin_amdgcn_mfma_f32_16x16x32_bf16(av, bv[u], acc, 0, 0, 0);
  }
  return acc;
}

__device__ __forceinline__ void rnn_body(const RnnArgs& P, int blk, char* smem) {
  char*   sW0 = smem;                              // Wxh slice (layer1)
  char*   sW1 = smem + 65536;                      // Whh slice
  __bf16* sP  = (__bf16*)(smem + 131072);          // [256] publish repack

  int tid = threadIdx.x;
  int lane = tid & 63, wave = tid >> 6;
  int mt = wave & 1, nt = wave >> 1;
  bool isL0 = (P.XP != nullptr);

  // one-time invalidate: kill stale L1/L2 lines from previous graph replays
  __builtin_amdgcn_fence(__ATOMIC_ACQUIRE, "agent");

  // ---- stage weight slices once, rows HL-MAJOR (lds row = hl*4 + gate)
  {
    const float* srcs[2] = {P.Wxh, P.Whh};
    char* dsts[2] = {sW0, sW1};
    for (int s = (isL0 ? 1 : 0); s < 2; ++s) {
      for (int g = 0; g < 4; ++g) {
        const float* sp = srcs[s] + (size_t)(g * 1024 + blk * 8) * 1024;
#pragma unroll
        for (int it = 0; it < 8; ++it) {
          int e = (it * 256 + tid) * 4;
          int rl = e >> 10, k = e & 1023;
          float4 v = *(const float4*)(sp + e);
          bf16x4 t4;
          t4[0] = (__bf16)v.x; t4[1] = (__bf16)v.y;
          t4[2] = (__bf16)v.z; t4[3] = (__bf16)v.w;
          int r = rl * 4 + g;   // hl-major
          *(bf16x4*)(dsts[s] + ((r << 11) + ((k << 1) ^ ((r & 7) << 4)))) = t4;
        }
      }
    }
  }

  // ---- cell ownership (swapped-MFMA C layout, verified R8/R10-R18):
  // lane -> hl = mt*4 + (lane>>4), b = nt*16 + (lane&15); acc[0..3]=i,f,g,o
  int hl = mt * 4 + (lane >> 4);
  int b  = nt * 16 + (lane & 15);
  float c = P.c0[b * 1024 + blk * 8 + hl];

  // layer1: per-thread gate biases (layer0 has them baked into XP)
  float bI = 0.f, bF = 0.f, bG = 0.f, bO = 0.f;
  if (!isL0) {
    int col = blk * 8 + hl;
    bI = P.bih[col] + P.bhh[col];
    bF = P.bih[1024 + col] + P.bhh[1024 + col];
    bG = P.bih[2048 + col] + P.bhh[2048 + col];
    bO = P.bih[3072 + col] + P.bhh[3072 + col];
  }

  int rr  = mt * 16 + (lane & 15);       // A (weight) row within 32-row slice
  int swz = (rr & 7) << 4;
  const char* aRow0 = sW0 + (rr << 11);
  const char* aRow1 = sW1 + (rr << 11);
  int kj   = (lane >> 4) * 16;           // A k-byte offset
  int bsub = (lane >> 4) * 512 + b * 16; // B (h) slab sub-offset

  // XP prefetch base (coalesced: [t][blk][hl][g][b], b = lane-contiguous)
  const __bf16* xpb = isL0 ? (P.XP + (size_t)blk * 1024 + hl * 128 + b) : nullptr;

  for (int t = 0; t < 128; ++t) {
    float xi = bI, xf = bF, xg = bG, xo = bO;
    if (isL0) {   // prefetch XP operands before the poll (in flight during it)
      const __bf16* xr = xpb + (size_t)t * 131072;
      xi = (float)xr[0];  xf = (float)xr[32];
      xg = (float)xr[64]; xo = (float)xr[96];
    }

    const char* hb = (const char*)((t == 0) ? P.h0
                                            : (P.hseq + (size_t)(t - 1) * SLAB)) + bsub;
    f32x4 acc = {0.f, 0.f, 0.f, 0.f};

    if (isL0) {
      // single poll (champion): own h_{t-1} from all 128 L0 blocks
      if (wave == 0 && t > 0) wait128(P.flags, (unsigned)t);
      __syncthreads();
      acc = accum_k1024_deep(acc, hb, aRow1, swz, kj);
    } else {
      // two-phase: x first (L0 runs ahead -> poll returns immediately),
      // own-h flag propagation hides behind the x accumulation.
      if (wave == 0) wait128(P.xflags, (unsigned)(t + 1));
      __syncthreads();
      const char* xb = (const char*)(P.xslab + (size_t)t * SLAB) + bsub;
      acc = accum_k1024_deep(acc, xb, aRow0, swz, kj);
      if (wave == 0 && t > 0) wait128(P.flags, (unsigned)t);
      __syncthreads();
      acc = accum_k1024_deep(acc, hb, aRow1, swz, kj);
    }

    // ---- pointwise LSTM cell, fully in registers (acc = i,f,g,o)
    float gi = sigmoidf_(acc[0] + xi);
    float gf = sigmoidf_(acc[1] + xf);
    float gg = tanhf_(acc[2] + xg);
    float go = sigmoidf_(acc[3] + xo);
    c = gf * c + gi * gg;
    float h = go * tanhf_(c);
    sP[b * 8 + hl] = (__bf16)h;    // repack [32 b][8 hl]
    __syncthreads();

    // ---- publish (champion): wave 0 only -- stores, OWN drain, flag.
    //      No trailing barrier; waves 1-3 run ahead.
    if (tid < 64) {
      unsigned long long v = *(const unsigned long long*)(sP + tid * 4);
      unsigned long long* dst = (unsigned long long*)(
          (char*)P.hseq + (size_t)t * 65536 + blk * 512 + tid * 8);
      __hip_atomic_store(dst, v, __ATOMIC_RELAXED, __HIP_MEMORY_SCOPE_AGENT);
      asm volatile("s_waitcnt vmcnt(0)" ::: "memory");
      if (tid == 0)
        __hip_atomic_store(P.flags + blk, (unsigned)(t + 1), __ATOMIC_RELEASE,
                           __HIP_MEMORY_SCOPE_AGENT);
    }
    // ---- yout (final decoder layer only): coalesced from sP
    if (P.yout) {
      int yb = tid >> 3, yhl = tid & 7;
      P.yout[((size_t)yb * 128 + t) * 1024 + blk * 8 + yhl] =
          (float)sP[yb * 8 + yhl];
    }
  }
  P.cfin[b * 1024 + blk * 8 + hl] = c;
}

// Blocks 0-127: layer0 (A). Blocks 128-255: layer1 (B), 1-step skewed.
__global__ __launch_bounds__(256, 1) void rnn_pair(RnnArgs A, RnnArgs B) {
  extern __shared__ char smem[];
  if (blockIdx.x < 128) rnn_body(A, blockIdx.x, smem);
  else                  rnn_body(B, blockIdx.x - 128, smem);
}

// ---------------------------------------------------------------------------
extern "C" void kernel_launch(void* const* d_in, const int* in_sizes, int n_in,
                              void* d_out, int out_size, void* d_ws, size_t ws_size,
                              hipStream_t stream) {
  (void)in_sizes; (void)n_in; (void)out_size; (void)ws_size;
  const int*   src     = (const int*)d_in[0];
  const int*   tgt     = (const int*)d_in[1];
  const float* enc_emb = (const float*)d_in[2];
  const float* dec_emb = (const float*)d_in[3];
  const float* W[16];
  for (int i = 0; i < 16; ++i) W[i] = (const float*)d_in[4 + i];
  // enc: Wih0=W[0] Whh0=W[1] bih0=W[2] bhh0=W[3]  Wih1=W[4] Whh1=W[5] b=W[6],W[7]
  // dec: Wih0=W[8] Whh0=W[9] b=W[10],W[11]        Wih1=W[12] Whh1=W[13] b=W[14],W[15]

  char* ws = (char*)d_ws;
  size_t off = 0;
  auto alloc = [&](size_t bytes) {
    char* p = ws + off;
    off += (bytes + 255) & ~(size_t)255;
    return p;
  };
  unsigned* flags = (unsigned*)alloc((size_t)4 * 128 * sizeof(unsigned));
  float*    zeros = (float*)alloc((size_t)32 * 1024 * 4);
  __bf16*   Xe   = (__bf16*)alloc((size_t)4096 * 512 * 2);
  __bf16*   Xd   = (__bf16*)alloc((size_t)4096 * 512 * 2);
  __bf16*   XP1  = (__bf16*)alloc((size_t)4096 * 4096 * 2);
  __bf16*   XP2  = (__bf16*)alloc((size_t)4096 * 4096 * 2);
  __bf16*   hE0  = (__bf16*)alloc((size_t)128 * SLAB * 2);
  __bf16*   hE1  = (__bf16*)alloc((size_t)128 * SLAB * 2);
  __bf16*   hD0  = (__bf16*)alloc((size_t)128 * SLAB * 2);
  __bf16*   hD1  = (__bf16*)alloc((size_t)128 * SLAB * 2);
  float*    cE0  = (float*)alloc((size_t)32 * 1024 * 4);
  float*    cE1  = (float*)alloc((size_t)32 * 1024 * 4);
  float*    cd0  = (float*)alloc((size_t)32 * 1024 * 4);
  float*    cd1  = (float*)alloc((size_t)32 * 1024 * 4);

  hipFuncSetAttribute((const void*)rnn_pair,
                      hipFuncAttributeMaxDynamicSharedMemorySize, RNN_SMEM);

  init_ws<<<128, 256, 0, stream>>>(zeros, flags);
  gather_emb<<<8192, 128, 0, stream>>>(src, tgt, enc_emb, dec_emb, Xe, Xd);

  // layer-0 x-parts (K=512) for both encoder and decoder, up front
  gemm_xp<<<1024, 256, 0, stream>>>(Xe, W[0], W[2], W[3], XP1, 512);
  gemm_xp<<<1024, 256, 0, stream>>>(Xd, W[8], W[10], W[11], XP2, 512);

  unsigned* fE0 = flags;
  unsigned* fE1 = flags + 128;
  unsigned* fD0 = flags + 256;
  unsigned* fD1 = flags + 384;

  // encoder epoch: L0 (blocks 0-127) + L1 skewed (blocks 128-255)
  RnnArgs e0{W[1], nullptr, nullptr, nullptr, XP1, nullptr, nullptr,
             (const __bf16*)zeros, zeros, hE0, cE0, nullptr, fE0};
  RnnArgs e1{W[5], W[4], W[6], W[7], nullptr, hE0, fE0,
             (const __bf16*)zeros, zeros, hE1, cE1, nullptr, fE1};
  rnn_pair<<<256, 256, RNN_SMEM, stream>>>(e0, e1);

  // decoder epoch: L0 init = encL0 finals, L1 init = encL1 finals -> d_out
  RnnArgs d0{W[9], nullptr, nullptr, nullptr, XP2, nullptr, nullptr,
             hE0 + (size_t)127 * SLAB, cE0, hD0, cd0, nullptr, fD0};
  RnnArgs d1{W[13], W[12], W[14], W[15], nullptr, hD0, fD0,
             hE1 + (size_t)127 * SLAB, cE1, hD1, cd1, (float*)d_out, fD1};
  rnn_pair<<<256, 256, RNN_SMEM, stream>>>(d0, d1);
}